// Round 4
// baseline (520.866 us; speedup 1.0000x reference)
//
#include <hip/hip_runtime.h>
#include <hip/hip_bf16.h>
#include <math.h>

typedef __bf16 bf16;
typedef __bf16 bf16x8 __attribute__((ext_vector_type(8)));
typedef __bf16 bf16x4 __attribute__((ext_vector_type(4)));
typedef float f32x4 __attribute__((ext_vector_type(4)));

#define KM 32768   // B*T
#define DIN 1088

#define BAR() asm volatile("s_barrier" ::: "memory")
#define WAIT_VM0() asm volatile("s_waitcnt vmcnt(0)" ::: "memory")

__device__ __forceinline__ void gload16(const void* g, void* l) {
  __builtin_amdgcn_global_load_lds((const __attribute__((address_space(1))) void*)g,
                                   (__attribute__((address_space(3))) void*)l, 16, 0, 0);
}

__device__ __forceinline__ float gelu_exact(float x) {
  return 0.5f * x * (1.0f + erff(x * 0.70710678118654752f));
}

// ---------------- fuse inputs -> bf16 [32768][1088] ----------------
__global__ void fuse_kernel(const float* __restrict__ tr, const float* __restrict__ se,
                            const float* __restrict__ pr, bf16* __restrict__ Xb) {
  int g = blockIdx.x * 256 + threadIdx.x;
  if (g >= KM * 272) return;
  int m = g / 272;
  int k0 = (g - m * 272) * 4;
  float4 v;
  if (k0 < 512)       v = *reinterpret_cast<const float4*>(tr + (size_t)m * 512 + k0);
  else if (k0 < 1024) v = *reinterpret_cast<const float4*>(se + (size_t)m * 512 + (k0 - 512));
  else                v = *reinterpret_cast<const float4*>(pr + (size_t)m * 64 + (k0 - 1024));
  union { bf16 h[4]; ushort4 u; } p;
  p.h[0] = (bf16)v.x; p.h[1] = (bf16)v.y; p.h[2] = (bf16)v.z; p.h[3] = (bf16)v.w;
  *reinterpret_cast<ushort4*>(Xb + (size_t)m * 1088 + k0) = p.u;
}

// ---------------- W[K][N] fp32 -> Wt[N][K] bf16 ----------------
__global__ void transpose_kernel(const float* __restrict__ W, bf16* __restrict__ Wt,
                                 int K, int N) {
  __shared__ float t[32][33];
  int k0 = blockIdx.x * 32, n0 = blockIdx.y * 32;
  int tx = threadIdx.x & 31, ty = threadIdx.x >> 5;  // 32 x 8
  #pragma unroll
  for (int j = 0; j < 32; j += 8) t[ty + j][tx] = W[(size_t)(k0 + ty + j) * N + n0 + tx];
  __syncthreads();
  #pragma unroll
  for (int j = 0; j < 32; j += 8)
    Wt[(size_t)(n0 + ty + j) * K + k0 + tx] = (bf16)t[tx][ty + j];
}

// ============ 256x256 MFMA GEMM, BK=64, 8 waves, 4-phase, early-staged dbuf ============
// A [M][K] bf16 row-major, Bt [N][K] bf16 row-major. C = A*B (+bias)(+act)(+res) -> bf16
// Schedule: at tile t phase 0, stage ALL of tile t+1 into buf (t+1)&1 (idle+dead
// during tile t). Single vmcnt(0) before the tile-boundary barrier (~3.5 phases of
// latency cover for every load; nothing recently-issued gets drained).
template<int ACT, bool RES>
__global__ __launch_bounds__(512, 2) void gemm256_kernel(
    const bf16* __restrict__ A, const bf16* __restrict__ Bt,
    const float* __restrict__ bias, const bf16* __restrict__ res,
    bf16* __restrict__ C, int N, int K, int nbn) {
  __shared__ __align__(16) bf16 ldsA[2][16384];   // [buf][256 rows][64] swizzled
  __shared__ __align__(16) bf16 ldsB[2][16384];
  int nwg = gridDim.x;                 // multiple of 8
  int bid = blockIdx.x;
  int nb = (bid & 7) * (nwg >> 3) + (bid >> 3);   // XCD chunked swizzle (bijective, nwg%8==0)
  int bn = nb % nbn, bm = nb / nbn;
  int tid = threadIdx.x;
  int w = tid >> 6, L = tid & 63;
  int wm = w >> 2, wn = w & 3;         // 2M x 4N waves; wave output 128x64
  const bf16* Ab = A + (size_t)bm * 256 * K;
  const bf16* Bb = Bt + (size_t)bn * 256 * K;
  int nkt = K >> 6;

  // stage one full K-tile (A 256x64 + B 256x64) = 8 gload16/thread.
  // Linear LDS dest, inverse-swizzled global source (ERRATA #21; conflicts=0 measured).
  int lr = L >> 3;
  int ce = ((L & 7) ^ lr) << 3;        // element col after inverse st-swizzle
  auto stage_tile = [&](int tt) {
    if (tt >= nkt) return;
    int bb = tt & 1;
    int k0 = tt << 6;
    #pragma unroll
    for (int j = 0; j < 2; ++j) {
      int rr = w * 16 + j * 8;         // wave-uniform LDS row base
      gload16(Ab + (size_t)(rr + lr) * K + k0 + ce,        &ldsA[bb][rr * 64]);
      gload16(Ab + (size_t)(128 + rr + lr) * K + k0 + ce,  &ldsA[bb][(128 + rr) * 64]);
      gload16(Bb + (size_t)(rr + lr) * K + k0 + ce,        &ldsB[bb][rr * 64]);
      gload16(Bb + (size_t)(128 + rr + lr) * K + k0 + ce,  &ldsB[bb][(128 + rr) * 64]);
    }
  };
  // swizzled ds_read of one 16x32 fragment slice (16B/lane)
  auto lread = [&](const bf16* base, int mrow, int kk) -> bf16x8 {
    int cb = ((kk << 6) + ((L >> 4) << 4)) ^ ((L & 7) << 4);
    return *reinterpret_cast<const bf16x8*>(
        reinterpret_cast<const char*>(base) + (mrow + (L & 15)) * 128 + cb);
  };

  f32x4 acc[8][4] = {};
  bf16x8 af[4][2], bq[4][2];

  // prologue: stage tile 0, drain, sync
  stage_tile(0);
  WAIT_VM0();
  BAR();

  for (int t = 0; t < nkt; ++t) {
    const bf16* As = ldsA[t & 1];
    const bf16* Bs = ldsB[t & 1];
    // ---- phase 0: read A-lo + B-lo; stage ALL of tile t+1; MFMA q00 ----
    #pragma unroll
    for (int mf = 0; mf < 4; ++mf)
      #pragma unroll
      for (int kk = 0; kk < 2; ++kk) af[mf][kk] = lread(As, wm * 128 + mf * 16, kk);
    #pragma unroll
    for (int nf = 0; nf < 2; ++nf)
      #pragma unroll
      for (int kk = 0; kk < 2; ++kk) bq[nf][kk] = lread(Bs, wn * 64 + nf * 16, kk);
    stage_tile(t + 1);
    BAR();
    __builtin_amdgcn_s_setprio(1);
    #pragma unroll
    for (int mf = 0; mf < 4; ++mf)
      #pragma unroll
      for (int nf = 0; nf < 2; ++nf)
        #pragma unroll
        for (int kk = 0; kk < 2; ++kk)
          acc[mf][nf] = __builtin_amdgcn_mfma_f32_16x16x32_bf16(af[mf][kk], bq[nf][kk], acc[mf][nf], 0, 0, 0);
    __builtin_amdgcn_s_setprio(0);
    BAR();
    // ---- phase 1: read B-hi; MFMA q01 ----
    #pragma unroll
    for (int nf = 2; nf < 4; ++nf)
      #pragma unroll
      for (int kk = 0; kk < 2; ++kk) bq[nf][kk] = lread(Bs, wn * 64 + nf * 16, kk);
    BAR();
    __builtin_amdgcn_s_setprio(1);
    #pragma unroll
    for (int mf = 0; mf < 4; ++mf)
      #pragma unroll
      for (int nf = 2; nf < 4; ++nf)
        #pragma unroll
        for (int kk = 0; kk < 2; ++kk)
          acc[mf][nf] = __builtin_amdgcn_mfma_f32_16x16x32_bf16(af[mf][kk], bq[nf][kk], acc[mf][nf], 0, 0, 0);
    __builtin_amdgcn_s_setprio(0);
    BAR();
    // ---- phase 2: read A-hi; MFMA q10 ----
    #pragma unroll
    for (int mf = 0; mf < 4; ++mf)
      #pragma unroll
      for (int kk = 0; kk < 2; ++kk) af[mf][kk] = lread(As, wm * 128 + 64 + mf * 16, kk);
    BAR();
    __builtin_amdgcn_s_setprio(1);
    #pragma unroll
    for (int mf = 0; mf < 4; ++mf)
      #pragma unroll
      for (int nf = 0; nf < 2; ++nf)
        #pragma unroll
        for (int kk = 0; kk < 2; ++kk)
          acc[4 + mf][nf] = __builtin_amdgcn_mfma_f32_16x16x32_bf16(af[mf][kk], bq[nf][kk], acc[4 + mf][nf], 0, 0, 0);
    __builtin_amdgcn_s_setprio(0);
    BAR();
    // ---- phase 3: register-only MFMA q11; then drain tile t+1 and cross ----
    __builtin_amdgcn_s_setprio(1);
    #pragma unroll
    for (int mf = 0; mf < 4; ++mf)
      #pragma unroll
      for (int nf = 2; nf < 4; ++nf)
        #pragma unroll
        for (int kk = 0; kk < 2; ++kk)
          acc[4 + mf][nf] = __builtin_amdgcn_mfma_f32_16x16x32_bf16(af[mf][kk], bq[nf][kk], acc[4 + mf][nf], 0, 0, 0);
    __builtin_amdgcn_s_setprio(0);
    WAIT_VM0();                        // tile t+1 fully landed (issued ~3.5 phases ago)
    BAR();
  }

  // ---- epilogue: D row = (L>>4)*4 + reg, col = L&15 ----
  int row0 = bm * 256 + wm * 128;
  int col0 = bn * 256 + wn * 64;
  float bv[4];
  #pragma unroll
  for (int nf = 0; nf < 4; ++nf) bv[nf] = bias[col0 + nf * 16 + (L & 15)];
  #pragma unroll
  for (int mf = 0; mf < 8; ++mf) {
    int grow = row0 + mf * 16 + ((L >> 4) << 2);
    #pragma unroll
    for (int rr = 0; rr < 4; ++rr) {
      size_t ro = (size_t)(grow + rr) * N;
      #pragma unroll
      for (int nf = 0; nf < 4; ++nf) {
        float v = acc[mf][nf][rr] + bv[nf];
        if (ACT == 1) v = gelu_exact(v);
        int col = col0 + nf * 16 + (L & 15);
        if (RES) v += (float)res[ro + col];
        C[ro + col] = (bf16)v;
      }
    }
  }
}

// ---------------- row LayerNorm in-place on bf16 [rows][1024] ----------------
__global__ void ln_inplace_kernel(bf16* __restrict__ X, const float* __restrict__ g,
                                  const float* __restrict__ b) {
  __shared__ float sb[4];
  size_t row = blockIdx.x;
  bf16* xr = X + row * 1024;
  int tid = threadIdx.x;
  bf16x4 xv = *reinterpret_cast<const bf16x4*>(xr + tid * 4);
  float x[4];
  #pragma unroll
  for (int i = 0; i < 4; ++i) x[i] = (float)xv[i];
  float s = x[0] + x[1] + x[2] + x[3];
  #pragma unroll
  for (int off = 32; off > 0; off >>= 1) s += __shfl_xor(s, off);
  if ((tid & 63) == 0) sb[tid >> 6] = s;
  __syncthreads();
  float mu = (sb[0] + sb[1] + sb[2] + sb[3]) * (1.0f / 1024.0f);
  __syncthreads();
  float d[4], sq = 0.f;
  #pragma unroll
  for (int i = 0; i < 4; ++i) { d[i] = x[i] - mu; sq += d[i] * d[i]; }
  #pragma unroll
  for (int off = 32; off > 0; off >>= 1) sq += __shfl_xor(sq, off);
  if ((tid & 63) == 0) sb[tid >> 6] = sq;
  __syncthreads();
  float var = (sb[0] + sb[1] + sb[2] + sb[3]) * (1.0f / 1024.0f);
  float rs = rsqrtf(var + 1e-5f);
  bf16x4 ov;
  #pragma unroll
  for (int i = 0; i < 4; ++i) ov[i] = (bf16)(d[i] * rs * g[tid * 4 + i] + b[tid * 4 + i]);
  *reinterpret_cast<bf16x4*>(xr + tid * 4) = ov;
}

// ---------------- objectness head: sigmoid(o1 . W2 + b2) ----------------
__global__ void obj_kernel(const bf16* __restrict__ o1, const float* __restrict__ W2,
                           const float* __restrict__ b2, float* __restrict__ obj,
                           float* __restrict__ out_obj) {
  __shared__ float w[512];
  int tid = threadIdx.x;
  w[tid] = W2[tid]; w[tid + 256] = W2[tid + 256];
  __syncthreads();
  int wv = tid >> 6, L = tid & 63;
  size_t m = (size_t)blockIdx.x * 4 + wv;
  bf16x8 v = *reinterpret_cast<const bf16x8*>(o1 + m * 512 + L * 8);
  float s = 0.f;
  #pragma unroll
  for (int j = 0; j < 8; ++j) s += (float)v[j] * w[L * 8 + j];
  #pragma unroll
  for (int off = 32; off > 0; off >>= 1) s += __shfl_xor(s, off);
  if (L == 0) {
    float o = 1.0f / (1.0f + expf(-(s + b2[0])));
    obj[m] = o; out_obj[m] = o;
  }
}

// ---------------- attn logits via MFMA: seq[32768x1024] @ tq^T[1024x16] ----------------
__global__ void attn_logits_mfma(const bf16* __restrict__ seq, const float* __restrict__ tq,
                                 const float* __restrict__ obj, float* __restrict__ logits) {
  __shared__ bf16 tqs[16][1032];
  int tid = threadIdx.x;
  for (int i = tid; i < 4096; i += 256) {
    int idx = i * 4;
    int n = idx >> 10, k = idx & 1023;
    float4 v = *reinterpret_cast<const float4*>(tq + idx);
    bf16x4 p; p[0] = (bf16)v.x; p[1] = (bf16)v.y; p[2] = (bf16)v.z; p[3] = (bf16)v.w;
    *reinterpret_cast<bf16x4*>(&tqs[n][k]) = p;
  }
  __syncthreads();
  int w = tid >> 6, L = tid & 63;
  int row0 = blockIdx.x * 128 + w * 32;
  const bf16* A0 = seq + (size_t)(row0 + (L & 15)) * 1024 + ((L >> 4) * 8);
  const bf16* Bq = &tqs[L & 15][(L >> 4) * 8];
  f32x4 acc0 = {}, acc1 = {};
  #pragma unroll 4
  for (int kt = 0; kt < 32; ++kt) {
    int k0 = kt * 32;
    bf16x8 bq = *reinterpret_cast<const bf16x8*>(Bq + k0);
    bf16x8 a0 = *reinterpret_cast<const bf16x8*>(A0 + k0);
    bf16x8 a1 = *reinterpret_cast<const bf16x8*>(A0 + 16 * 1024 + k0);
    acc0 = __builtin_amdgcn_mfma_f32_16x16x32_bf16(a0, bq, acc0, 0, 0, 0);
    acc1 = __builtin_amdgcn_mfma_f32_16x16x32_bf16(a1, bq, acc1, 0, 0, 0);
  }
  int b = row0 >> 12;
  int n = L & 15;
  float* outn = logits + ((size_t)(b * 16) + n) * 4096;
  #pragma unroll
  for (int mf = 0; mf < 2; ++mf) {
    int mrow = row0 + mf * 16 + ((L >> 4) << 2);
    #pragma unroll
    for (int r = 0; r < 4; ++r) {
      int m = mrow + r;
      float v = (mf == 0 ? acc0[r] : acc1[r]) * 0.03125f + 1.5f * obj[m];
      outn[m & 4095] = v;
    }
  }
}

// ---------------- softmax over T=4096 per (b,n) ----------------
__global__ void softmax_kernel(const float* __restrict__ logits, float* __restrict__ attn) {
  __shared__ float sb[4];
  size_t row = blockIdx.x;
  const float* lr = logits + row * 4096;
  float* orow = attn + row * 4096;
  int tid = threadIdx.x;
  float x[16];
  #pragma unroll
  for (int i = 0; i < 4; ++i) {
    float4 v = *reinterpret_cast<const float4*>(lr + tid * 16 + i * 4);
    x[i * 4 + 0] = v.x; x[i * 4 + 1] = v.y; x[i * 4 + 2] = v.z; x[i * 4 + 3] = v.w;
  }
  float mx = -1e30f;
  #pragma unroll
  for (int j = 0; j < 16; ++j) mx = fmaxf(mx, x[j]);
  #pragma unroll
  for (int off = 32; off > 0; off >>= 1) mx = fmaxf(mx, __shfl_xor(mx, off));
  if ((tid & 63) == 0) sb[tid >> 6] = mx;
  __syncthreads();
  mx = fmaxf(fmaxf(sb[0], sb[1]), fmaxf(sb[2], sb[3]));
  __syncthreads();
  float s = 0.f;
  #pragma unroll
  for (int j = 0; j < 16; ++j) { x[j] = expf(x[j] - mx); s += x[j]; }
  #pragma unroll
  for (int off = 32; off > 0; off >>= 1) s += __shfl_xor(s, off);
  if ((tid & 63) == 0) sb[tid >> 6] = s;
  __syncthreads();
  float inv = 1.0f / (sb[0] + sb[1] + sb[2] + sb[3]);
  #pragma unroll
  for (int i = 0; i < 4; ++i) {
    float4 v = make_float4(x[i * 4] * inv, x[i * 4 + 1] * inv, x[i * 4 + 2] * inv, x[i * 4 + 3] * inv);
    *reinterpret_cast<float4*>(orow + tid * 16 + i * 4) = v;
  }
}

// ---------------- token_values: sum_t attn[b,n,t]*seq[b,t,h], T split 4 ways ----------------
__global__ void token_values_kernel(const float* __restrict__ attn, const bf16* __restrict__ seq,
                                    float* __restrict__ tvp) {
  int bid = blockIdx.x;
  int split = bid & 3;
  int hc = (bid >> 2) & 15;
  int b = bid >> 6;
  __shared__ float al[16][256];
  int h = hc * 64 + (threadIdx.x & 63);
  int grp = threadIdx.x >> 6;
  float acc[4] = {0.f, 0.f, 0.f, 0.f};
  for (int c = 0; c < 4; ++c) {
    int t0 = split * 1024 + c * 256;
    __syncthreads();
    for (int i = threadIdx.x; i < 4096; i += 256)
      al[i >> 8][i & 255] = attn[((size_t)b * 16 + (i >> 8)) * 4096 + t0 + (i & 255)];
    __syncthreads();
    for (int tt = 0; tt < 256; ++tt) {
      float s = (float)seq[((size_t)b * 4096 + t0 + tt) * 1024 + h];
      #pragma unroll
      for (int i = 0; i < 4; ++i) acc[i] += al[grp * 4 + i][tt] * s;
    }
  }
  #pragma unroll
  for (int i = 0; i < 4; ++i)
    tvp[(size_t)split * 131072 + ((size_t)b * 16 + grp * 4 + i) * 1024 + h] = acc[i];
}

// ---------------- final LN: LN(tq + sum_parts(tv)) -> fp32 out ----------------
__global__ void final_ln_kernel(const float* __restrict__ tq, const float* __restrict__ tvp,
                                const float* __restrict__ g, const float* __restrict__ bb,
                                float* __restrict__ out0) {
  __shared__ float sb[4];
  int row = blockIdx.x;
  int n = row & 15;
  int tid = threadIdx.x;
  float x[4];
  #pragma unroll
  for (int i = 0; i < 4; ++i) {
    int h = tid * 4 + i;
    float v = tq[n * 1024 + h];
    #pragma unroll
    for (int p = 0; p < 4; ++p) v += tvp[(size_t)p * 131072 + (size_t)row * 1024 + h];
    x[i] = v;
  }
  float s = x[0] + x[1] + x[2] + x[3];
  #pragma unroll
  for (int off = 32; off > 0; off >>= 1) s += __shfl_xor(s, off);
  if ((tid & 63) == 0) sb[tid >> 6] = s;
  __syncthreads();
  float mu = (sb[0] + sb[1] + sb[2] + sb[3]) * (1.0f / 1024.0f);
  __syncthreads();
  float d[4], sq = 0.f;
  #pragma unroll
  for (int i = 0; i < 4; ++i) { d[i] = x[i] - mu; sq += d[i] * d[i]; }
  #pragma unroll
  for (int off = 32; off > 0; off >>= 1) sq += __shfl_xor(sq, off);
  if ((tid & 63) == 0) sb[tid >> 6] = sq;
  __syncthreads();
  float var = (sb[0] + sb[1] + sb[2] + sb[3]) * (1.0f / 1024.0f);
  float rs = rsqrtf(var + 1e-5f);
  #pragma unroll
  for (int i = 0; i < 4; ++i) {
    int h = tid * 4 + i;
    out0[(size_t)row * 1024 + h] = d[i] * rs * g[h] + bb[h];
  }
}

extern "C" void kernel_launch(void* const* d_in, const int* in_sizes, int n_in,
                              void* d_out, int out_size, void* d_ws, size_t ws_size,
                              hipStream_t stream) {
  const float* tr      = (const float*)d_in[0];
  const float* se      = (const float*)d_in[1];
  const float* pr      = (const float*)d_in[2];
  const float* W_in    = (const float*)d_in[3];
  const float* b_in    = (const float*)d_in[4];
  const float* ln_in_g = (const float*)d_in[5];
  const float* ln_in_b = (const float*)d_in[6];
  const float* W_m1    = (const float*)d_in[7];
  const float* b_m1    = (const float*)d_in[8];
  const float* W_m2    = (const float*)d_in[9];
  const float* b_m2    = (const float*)d_in[10];
  const float* W_o1    = (const float*)d_in[11];
  const float* b_o1    = (const float*)d_in[12];
  const float* W_o2    = (const float*)d_in[13];
  const float* b_o2    = (const float*)d_in[14];
  const float* tq      = (const float*)d_in[15];
  const float* ln_out_g= (const float*)d_in[16];
  const float* ln_out_b= (const float*)d_in[17];

  float* out       = (float*)d_out;
  float* out_state = out;                       // [8,16,1024]
  float* out_attn  = out + 131072;              // [8,16,4096]
  float* out_obj   = out + 131072 + 524288;     // [8,4096]

  char* ws = (char*)d_ws;
  size_t off = 0;
  auto alloc = [&](size_t bytes) {
    char* p = ws + off;
    off += (bytes + 255) & ~(size_t)255;
    return p;
  };
  bf16*  Xb   = (bf16*)alloc(71303168);   // fused input; later reused as t1
  bf16*  t1   = Xb;
  bf16*  hb   = (bf16*)alloc(67108864);   // h; later reused as o1
  bf16*  o1   = hb;
  bf16*  sq   = (bf16*)alloc(67108864);   // h+mlp -> seq_hidden (LN in place)
  bf16*  WbIn = (bf16*)alloc(2228224);
  bf16*  WbM1 = (bf16*)alloc(2097152);
  bf16*  WbM2 = (bf16*)alloc(2097152);
  bf16*  WbO1 = (bf16*)alloc(1048576);
  float* objw = (float*)alloc(131072 * 4);
  float* logw = (float*)alloc(2097152);
  float* tvp  = (float*)alloc(2097152);

  fuse_kernel<<<(KM * 272 + 255) / 256, 256, 0, stream>>>(tr, se, pr, Xb);
  transpose_kernel<<<dim3(34, 32), 256, 0, stream>>>(W_in, WbIn, 1088, 1024);
  transpose_kernel<<<dim3(32, 32), 256, 0, stream>>>(W_m1, WbM1, 1024, 1024);
  transpose_kernel<<<dim3(32, 32), 256, 0, stream>>>(W_m2, WbM2, 1024, 1024);
  transpose_kernel<<<dim3(32, 16), 256, 0, stream>>>(W_o1, WbO1, 1024, 512);

  // h = fused@W_in + b_in              grid = (32768/256)*(1024/256) = 512
  gemm256_kernel<0, false><<<512, 512, 0, stream>>>(Xb, WbIn, b_in, nullptr, hb, 1024, 1088, 4);
  // t1 = gelu(h@W_m1 + b_m1)
  gemm256_kernel<1, false><<<512, 512, 0, stream>>>(hb, WbM1, b_m1, nullptr, t1, 1024, 1024, 4);
  // s = h + (t1@W_m2 + b_m2)
  gemm256_kernel<0, true ><<<512, 512, 0, stream>>>(t1, WbM2, b_m2, hb, sq, 1024, 1024, 4);
  // seq_hidden = LN(s)
  ln_inplace_kernel<<<32768, 256, 0, stream>>>(sq, ln_in_g, ln_in_b);
  // o1 = gelu(seq@W_o1 + b_o1)         grid = 128*2 = 256
  gemm256_kernel<1, false><<<256, 512, 0, stream>>>(sq, WbO1, b_o1, nullptr, o1, 512, 1024, 2);
  // objectness
  obj_kernel<<<8192, 256, 0, stream>>>(o1, W_o2, b_o2, objw, out_obj);
  // attn logits (MFMA) + softmax
  attn_logits_mfma<<<256, 256, 0, stream>>>(sq, tq, objw, logw);
  softmax_kernel<<<128, 256, 0, stream>>>(logw, out_attn);
  // token values + final LN
  token_values_kernel<<<512, 256, 0, stream>>>(out_attn, sq, tvp);
  final_ln_kernel<<<128, 256, 0, stream>>>(tq, tvp, ln_out_g, ln_out_b, out_state);
}

// Round 5
// 438.314 us; speedup vs baseline: 1.1883x; 1.1883x over previous
//
#include <hip/hip_runtime.h>
#include <hip/hip_bf16.h>
#include <math.h>

typedef __bf16 bf16;
typedef __bf16 bf16x8 __attribute__((ext_vector_type(8)));
typedef __bf16 bf16x4 __attribute__((ext_vector_type(4)));
typedef float f32x4 __attribute__((ext_vector_type(4)));

#define KM 32768   // B*T
#define DIN 1088

__device__ __forceinline__ void gload16(const void* g, void* l) {
  __builtin_amdgcn_global_load_lds((const __attribute__((address_space(1))) void*)g,
                                   (__attribute__((address_space(3))) void*)l, 16, 0, 0);
}

__device__ __forceinline__ float gelu_exact(float x) {
  return 0.5f * x * (1.0f + erff(x * 0.70710678118654752f));
}

// ---------------- fuse inputs -> bf16 [32768][1088] ----------------
__global__ void fuse_kernel(const float* __restrict__ tr, const float* __restrict__ se,
                            const float* __restrict__ pr, bf16* __restrict__ Xb) {
  int g = blockIdx.x * 256 + threadIdx.x;
  if (g >= KM * 272) return;
  int m = g / 272;
  int k0 = (g - m * 272) * 4;
  float4 v;
  if (k0 < 512)       v = *reinterpret_cast<const float4*>(tr + (size_t)m * 512 + k0);
  else if (k0 < 1024) v = *reinterpret_cast<const float4*>(se + (size_t)m * 512 + (k0 - 512));
  else                v = *reinterpret_cast<const float4*>(pr + (size_t)m * 64 + (k0 - 1024));
  union { bf16 h[4]; ushort4 u; } p;
  p.h[0] = (bf16)v.x; p.h[1] = (bf16)v.y; p.h[2] = (bf16)v.z; p.h[3] = (bf16)v.w;
  *reinterpret_cast<ushort4*>(Xb + (size_t)m * 1088 + k0) = p.u;
}

// ---------------- W[K][N] fp32 -> Wt[N][K] bf16 ----------------
__global__ void transpose_kernel(const float* __restrict__ W, bf16* __restrict__ Wt,
                                 int K, int N) {
  __shared__ float t[32][33];
  int k0 = blockIdx.x * 32, n0 = blockIdx.y * 32;
  int tx = threadIdx.x & 31, ty = threadIdx.x >> 5;  // 32 x 8
  #pragma unroll
  for (int j = 0; j < 32; j += 8) t[ty + j][tx] = W[(size_t)(k0 + ty + j) * N + n0 + tx];
  __syncthreads();
  #pragma unroll
  for (int j = 0; j < 32; j += 8)
    Wt[(size_t)(n0 + ty + j) * K + k0 + tx] = (bf16)t[tx][ty + j];
}

// ---------------- 128x128 MFMA GEMM, BK=64, 4 waves (proven R2 structure) ----------------
// + T1: XCD-chunked bijective block swizzle so the 8 bn-blocks sharing an A-panel
//   run consecutively on ONE XCD (A-panel L2-resident; B 2MB L2-resident).
// A [M][K] bf16 row-major, Bt [N][K] bf16 row-major. C = A*B (+bias)(+act)(+res) -> bf16
template<int ACT, bool RES>
__global__ void gemm_kernel(const bf16* __restrict__ A, const bf16* __restrict__ Bt,
                            const float* __restrict__ bias, const bf16* __restrict__ res,
                            bf16* __restrict__ C, int N, int K, int nbn) {
  __shared__ __align__(16) bf16 lds[2][128 * 64];
  int nwg = gridDim.x;
  int bid0 = blockIdx.x;
  // chunked XCD swizzle (bijective when nwg%8==0; identity otherwise)
  int bid = (nwg & 7) ? bid0 : ((bid0 & 7) * (nwg >> 3) + (bid0 >> 3));
  int bn = bid % nbn, bm = bid / nbn;
  int tid = threadIdx.x;
  int w = tid >> 6, L = tid & 63;
  int wm = w >> 1, wn = w & 1;
  // staging: inverse-swizzled global source, linear LDS dest (ERRATA #21)
  int srow = L >> 3;                 // row within 8-row group
  int scol = 8 * ((L & 7) ^ srow);   // element col after inverse st-swizzle
  const bf16* Ab = A + (size_t)(bm * 128) * K;
  const bf16* Bb = Bt + (size_t)(bn * 128) * K;
  f32x4 acc[4][4] = {};
  int nkt = K >> 6;
  for (int kt = 0; kt < nkt; ++kt) {
    int k0 = kt << 6;
    #pragma unroll
    for (int i = 0; i < 4; ++i) {
      int row = w * 32 + i * 8;
      gload16(Ab + (size_t)(row + srow) * K + k0 + scol, &lds[0][row * 64]);
      gload16(Bb + (size_t)(row + srow) * K + k0 + scol, &lds[1][row * 64]);
    }
    __syncthreads();   // compiler drains vmcnt before s_barrier
    #pragma unroll
    for (int kk = 0; kk < 2; ++kk) {
      bf16x8 af[4], bfr[4];
      int cb = kk * 64 + ((L >> 4) * 16);   // byte col within 128B row
      #pragma unroll
      for (int m = 0; m < 4; ++m) {
        int r = wm * 64 + m * 16 + (L & 15);
        int addr = r * 128 + (cb ^ ((r & 7) << 4));
        af[m] = *reinterpret_cast<const bf16x8*>(
            reinterpret_cast<const char*>(&lds[0][0]) + addr);
      }
      #pragma unroll
      for (int n = 0; n < 4; ++n) {
        int r = wn * 64 + n * 16 + (L & 15);
        int addr = r * 128 + (cb ^ ((r & 7) << 4));
        bfr[n] = *reinterpret_cast<const bf16x8*>(
            reinterpret_cast<const char*>(&lds[1][0]) + addr);
      }
      #pragma unroll
      for (int m = 0; m < 4; ++m)
        #pragma unroll
        for (int n = 0; n < 4; ++n)
          acc[m][n] = __builtin_amdgcn_mfma_f32_16x16x32_bf16(af[m], bfr[n], acc[m][n], 0, 0, 0);
    }
    __syncthreads();
  }
  // epilogue: D row = (L>>4)*4 + reg, col = L&15  [m89-verified layout]
  int cn0 = bn * 128 + wn * 64;
  float bv[4];
  #pragma unroll
  for (int n = 0; n < 4; ++n) bv[n] = bias[cn0 + n * 16 + (L & 15)];
  #pragma unroll
  for (int m = 0; m < 4; ++m) {
    int grow0 = bm * 128 + wm * 64 + m * 16 + ((L >> 4) << 2);
    #pragma unroll
    for (int r = 0; r < 4; ++r) {
      size_t ro = (size_t)(grow0 + r) * N;
      #pragma unroll
      for (int n = 0; n < 4; ++n) {
        float v = acc[m][n][r] + bv[n];
        if (ACT == 1) v = gelu_exact(v);
        int col = cn0 + n * 16 + (L & 15);
        if (RES) v += (float)res[ro + col];
        C[ro + col] = (bf16)v;
      }
    }
  }
}

// ---------------- row LayerNorm in-place on bf16 [rows][1024] ----------------
__global__ void ln_inplace_kernel(bf16* __restrict__ X, const float* __restrict__ g,
                                  const float* __restrict__ b) {
  __shared__ float sb[4];
  size_t row = blockIdx.x;
  bf16* xr = X + row * 1024;
  int tid = threadIdx.x;
  bf16x4 xv = *reinterpret_cast<const bf16x4*>(xr + tid * 4);
  float x[4];
  #pragma unroll
  for (int i = 0; i < 4; ++i) x[i] = (float)xv[i];
  float s = x[0] + x[1] + x[2] + x[3];
  #pragma unroll
  for (int off = 32; off > 0; off >>= 1) s += __shfl_xor(s, off);
  if ((tid & 63) == 0) sb[tid >> 6] = s;
  __syncthreads();
  float mu = (sb[0] + sb[1] + sb[2] + sb[3]) * (1.0f / 1024.0f);
  __syncthreads();
  float d[4], sq = 0.f;
  #pragma unroll
  for (int i = 0; i < 4; ++i) { d[i] = x[i] - mu; sq += d[i] * d[i]; }
  #pragma unroll
  for (int off = 32; off > 0; off >>= 1) sq += __shfl_xor(sq, off);
  if ((tid & 63) == 0) sb[tid >> 6] = sq;
  __syncthreads();
  float var = (sb[0] + sb[1] + sb[2] + sb[3]) * (1.0f / 1024.0f);
  float rs = rsqrtf(var + 1e-5f);
  bf16x4 ov;
  #pragma unroll
  for (int i = 0; i < 4; ++i) ov[i] = (bf16)(d[i] * rs * g[tid * 4 + i] + b[tid * 4 + i]);
  *reinterpret_cast<bf16x4*>(xr + tid * 4) = ov;
}

// ---------------- objectness head: sigmoid(o1 . W2 + b2) ----------------
__global__ void obj_kernel(const bf16* __restrict__ o1, const float* __restrict__ W2,
                           const float* __restrict__ b2, float* __restrict__ obj,
                           float* __restrict__ out_obj) {
  __shared__ float w[512];
  int tid = threadIdx.x;
  w[tid] = W2[tid]; w[tid + 256] = W2[tid + 256];
  __syncthreads();
  int wv = tid >> 6, L = tid & 63;
  size_t m = (size_t)blockIdx.x * 4 + wv;
  bf16x8 v = *reinterpret_cast<const bf16x8*>(o1 + m * 512 + L * 8);
  float s = 0.f;
  #pragma unroll
  for (int j = 0; j < 8; ++j) s += (float)v[j] * w[L * 8 + j];
  #pragma unroll
  for (int off = 32; off > 0; off >>= 1) s += __shfl_xor(s, off);
  if (L == 0) {
    float o = 1.0f / (1.0f + expf(-(s + b2[0])));
    obj[m] = o; out_obj[m] = o;
  }
}

// ---------------- attn logits via MFMA: seq[32768x1024] @ tq^T[1024x16] ----------------
__global__ void attn_logits_mfma(const bf16* __restrict__ seq, const float* __restrict__ tq,
                                 const float* __restrict__ obj, float* __restrict__ logits) {
  __shared__ bf16 tqs[16][1032];
  int tid = threadIdx.x;
  for (int i = tid; i < 4096; i += 256) {
    int idx = i * 4;
    int n = idx >> 10, k = idx & 1023;
    float4 v = *reinterpret_cast<const float4*>(tq + idx);
    bf16x4 p; p[0] = (bf16)v.x; p[1] = (bf16)v.y; p[2] = (bf16)v.z; p[3] = (bf16)v.w;
    *reinterpret_cast<bf16x4*>(&tqs[n][k]) = p;
  }
  __syncthreads();
  int w = tid >> 6, L = tid & 63;
  int row0 = blockIdx.x * 128 + w * 32;
  const bf16* A0 = seq + (size_t)(row0 + (L & 15)) * 1024 + ((L >> 4) * 8);
  const bf16* Bq = &tqs[L & 15][(L >> 4) * 8];
  f32x4 acc0 = {}, acc1 = {};
  #pragma unroll 4
  for (int kt = 0; kt < 32; ++kt) {
    int k0 = kt * 32;
    bf16x8 bq = *reinterpret_cast<const bf16x8*>(Bq + k0);
    bf16x8 a0 = *reinterpret_cast<const bf16x8*>(A0 + k0);
    bf16x8 a1 = *reinterpret_cast<const bf16x8*>(A0 + 16 * 1024 + k0);
    acc0 = __builtin_amdgcn_mfma_f32_16x16x32_bf16(a0, bq, acc0, 0, 0, 0);
    acc1 = __builtin_amdgcn_mfma_f32_16x16x32_bf16(a1, bq, acc1, 0, 0, 0);
  }
  int b = row0 >> 12;
  int n = L & 15;
  float* outn = logits + ((size_t)(b * 16) + n) * 4096;
  #pragma unroll
  for (int mf = 0; mf < 2; ++mf) {
    int mrow = row0 + mf * 16 + ((L >> 4) << 2);
    #pragma unroll
    for (int r = 0; r < 4; ++r) {
      int m = mrow + r;
      float v = (mf == 0 ? acc0[r] : acc1[r]) * 0.03125f + 1.5f * obj[m];
      outn[m & 4095] = v;
    }
  }
}

// ---------------- softmax over T=4096 per (b,n) ----------------
__global__ void softmax_kernel(const float* __restrict__ logits, float* __restrict__ attn) {
  __shared__ float sb[4];
  size_t row = blockIdx.x;
  const float* lr = logits + row * 4096;
  float* orow = attn + row * 4096;
  int tid = threadIdx.x;
  float x[16];
  #pragma unroll
  for (int i = 0; i < 4; ++i) {
    float4 v = *reinterpret_cast<const float4*>(lr + tid * 16 + i * 4);
    x[i * 4 + 0] = v.x; x[i * 4 + 1] = v.y; x[i * 4 + 2] = v.z; x[i * 4 + 3] = v.w;
  }
  float mx = -1e30f;
  #pragma unroll
  for (int j = 0; j < 16; ++j) mx = fmaxf(mx, x[j]);
  #pragma unroll
  for (int off = 32; off > 0; off >>= 1) mx = fmaxf(mx, __shfl_xor(mx, off));
  if ((tid & 63) == 0) sb[tid >> 6] = mx;
  __syncthreads();
  mx = fmaxf(fmaxf(sb[0], sb[1]), fmaxf(sb[2], sb[3]));
  __syncthreads();
  float s = 0.f;
  #pragma unroll
  for (int j = 0; j < 16; ++j) { x[j] = expf(x[j] - mx); s += x[j]; }
  #pragma unroll
  for (int off = 32; off > 0; off >>= 1) s += __shfl_xor(s, off);
  if ((tid & 63) == 0) sb[tid >> 6] = s;
  __syncthreads();
  float inv = 1.0f / (sb[0] + sb[1] + sb[2] + sb[3]);
  #pragma unroll
  for (int i = 0; i < 4; ++i) {
    float4 v = make_float4(x[i * 4] * inv, x[i * 4 + 1] * inv, x[i * 4 + 2] * inv, x[i * 4 + 3] * inv);
    *reinterpret_cast<float4*>(orow + tid * 16 + i * 4) = v;
  }
}

// ---------------- token_values: sum_t attn[b,n,t]*seq[b,t,h], T split 4 ways ----------------
__global__ void token_values_kernel(const float* __restrict__ attn, const bf16* __restrict__ seq,
                                    float* __restrict__ tvp) {
  int bid = blockIdx.x;
  int split = bid & 3;
  int hc = (bid >> 2) & 15;
  int b = bid >> 6;
  __shared__ float al[16][256];
  int h = hc * 64 + (threadIdx.x & 63);
  int grp = threadIdx.x >> 6;
  float acc[4] = {0.f, 0.f, 0.f, 0.f};
  for (int c = 0; c < 4; ++c) {
    int t0 = split * 1024 + c * 256;
    __syncthreads();
    for (int i = threadIdx.x; i < 4096; i += 256)
      al[i >> 8][i & 255] = attn[((size_t)b * 16 + (i >> 8)) * 4096 + t0 + (i & 255)];
    __syncthreads();
    for (int tt = 0; tt < 256; ++tt) {
      float s = (float)seq[((size_t)b * 4096 + t0 + tt) * 1024 + h];
      #pragma unroll
      for (int i = 0; i < 4; ++i) acc[i] += al[grp * 4 + i][tt] * s;
    }
  }
  #pragma unroll
  for (int i = 0; i < 4; ++i)
    tvp[(size_t)split * 131072 + ((size_t)b * 16 + grp * 4 + i) * 1024 + h] = acc[i];
}

// ---------------- final LN: LN(tq + sum_parts(tv)) -> fp32 out ----------------
__global__ void final_ln_kernel(const float* __restrict__ tq, const float* __restrict__ tvp,
                                const float* __restrict__ g, const float* __restrict__ bb,
                                float* __restrict__ out0) {
  __shared__ float sb[4];
  int row = blockIdx.x;
  int n = row & 15;
  int tid = threadIdx.x;
  float x[4];
  #pragma unroll
  for (int i = 0; i < 4; ++i) {
    int h = tid * 4 + i;
    float v = tq[n * 1024 + h];
    #pragma unroll
    for (int p = 0; p < 4; ++p) v += tvp[(size_t)p * 131072 + (size_t)row * 1024 + h];
    x[i] = v;
  }
  float s = x[0] + x[1] + x[2] + x[3];
  #pragma unroll
  for (int off = 32; off > 0; off >>= 1) s += __shfl_xor(s, off);
  if ((tid & 63) == 0) sb[tid >> 6] = s;
  __syncthreads();
  float mu = (sb[0] + sb[1] + sb[2] + sb[3]) * (1.0f / 1024.0f);
  __syncthreads();
  float d[4], sq = 0.f;
  #pragma unroll
  for (int i = 0; i < 4; ++i) { d[i] = x[i] - mu; sq += d[i] * d[i]; }
  #pragma unroll
  for (int off = 32; off > 0; off >>= 1) sq += __shfl_xor(sq, off);
  if ((tid & 63) == 0) sb[tid >> 6] = sq;
  __syncthreads();
  float var = (sb[0] + sb[1] + sb[2] + sb[3]) * (1.0f / 1024.0f);
  float rs = rsqrtf(var + 1e-5f);
  #pragma unroll
  for (int i = 0; i < 4; ++i) {
    int h = tid * 4 + i;
    out0[(size_t)row * 1024 + h] = d[i] * rs * g[h] + bb[h];
  }
}

extern "C" void kernel_launch(void* const* d_in, const int* in_sizes, int n_in,
                              void* d_out, int out_size, void* d_ws, size_t ws_size,
                              hipStream_t stream) {
  const float* tr      = (const float*)d_in[0];
  const float* se      = (const float*)d_in[1];
  const float* pr      = (const float*)d_in[2];
  const float* W_in    = (const float*)d_in[3];
  const float* b_in    = (const float*)d_in[4];
  const float* ln_in_g = (const float*)d_in[5];
  const float* ln_in_b = (const float*)d_in[6];
  const float* W_m1    = (const float*)d_in[7];
  const float* b_m1    = (const float*)d_in[8];
  const float* W_m2    = (const float*)d_in[9];
  const float* b_m2    = (const float*)d_in[10];
  const float* W_o1    = (const float*)d_in[11];
  const float* b_o1    = (const float*)d_in[12];
  const float* W_o2    = (const float*)d_in[13];
  const float* b_o2    = (const float*)d_in[14];
  const float* tq      = (const float*)d_in[15];
  const float* ln_out_g= (const float*)d_in[16];
  const float* ln_out_b= (const float*)d_in[17];

  float* out       = (float*)d_out;
  float* out_state = out;                       // [8,16,1024]
  float* out_attn  = out + 131072;              // [8,16,4096]
  float* out_obj   = out + 131072 + 524288;     // [8,4096]

  char* ws = (char*)d_ws;
  size_t off = 0;
  auto alloc = [&](size_t bytes) {
    char* p = ws + off;
    off += (bytes + 255) & ~(size_t)255;
    return p;
  };
  bf16*  Xb   = (bf16*)alloc(71303168);   // fused input; later reused as t1
  bf16*  t1   = Xb;
  bf16*  hb   = (bf16*)alloc(67108864);   // h; later reused as o1
  bf16*  o1   = hb;
  bf16*  sq   = (bf16*)alloc(67108864);   // h+mlp -> seq_hidden (LN in place)
  bf16*  WbIn = (bf16*)alloc(2228224);
  bf16*  WbM1 = (bf16*)alloc(2097152);
  bf16*  WbM2 = (bf16*)alloc(2097152);
  bf16*  WbO1 = (bf16*)alloc(1048576);
  float* objw = (float*)alloc(131072 * 4);
  float* logw = (float*)alloc(2097152);
  float* tvp  = (float*)alloc(2097152);

  fuse_kernel<<<(KM * 272 + 255) / 256, 256, 0, stream>>>(tr, se, pr, Xb);
  transpose_kernel<<<dim3(34, 32), 256, 0, stream>>>(W_in, WbIn, 1088, 1024);
  transpose_kernel<<<dim3(32, 32), 256, 0, stream>>>(W_m1, WbM1, 1024, 1024);
  transpose_kernel<<<dim3(32, 32), 256, 0, stream>>>(W_m2, WbM2, 1024, 1024);
  transpose_kernel<<<dim3(32, 16), 256, 0, stream>>>(W_o1, WbO1, 1024, 512);

  // h = fused@W_in + b_in
  gemm_kernel<0, false><<<256 * 8, 256, 0, stream>>>(Xb, WbIn, b_in, nullptr, hb, 1024, 1088, 8);
  // t1 = gelu(h@W_m1 + b_m1)
  gemm_kernel<1, false><<<256 * 8, 256, 0, stream>>>(hb, WbM1, b_m1, nullptr, t1, 1024, 1024, 8);
  // s = h + (t1@W_m2 + b_m2)
  gemm_kernel<0, true ><<<256 * 8, 256, 0, stream>>>(t1, WbM2, b_m2, hb, sq, 1024, 1024, 8);
  // seq_hidden = LN(s)
  ln_inplace_kernel<<<32768, 256, 0, stream>>>(sq, ln_in_g, ln_in_b);
  // o1 = gelu(seq@W_o1 + b_o1)
  gemm_kernel<1, false><<<256 * 4, 256, 0, stream>>>(sq, WbO1, b_o1, nullptr, o1, 512, 1024, 4);
  // objectness
  obj_kernel<<<8192, 256, 0, stream>>>(o1, W_o2, b_o2, objw, out_obj);
  // attn logits (MFMA) + softmax
  attn_logits_mfma<<<256, 256, 0, stream>>>(sq, tq, objw, logw);
  softmax_kernel<<<128, 256, 0, stream>>>(logw, out_attn);
  // token values + final LN
  token_values_kernel<<<512, 256, 0, stream>>>(out_attn, sq, tvp);
  final_ln_kernel<<<128, 256, 0, stream>>>(tq, tvp, ln_out_g, ln_out_b, out_state);
}